// Round 1
// baseline (1724.659 us; speedup 1.0000x reference)
//
#include <hip/hip_runtime.h>
#include <cmath>

#define T_TOK 8192
#define DMODEL 1024
#define NHEAD 8
#define DH 128
#define NEXP 8
#define NNE 64      // NHEAD*NEXP
#define DHID 512

// ---------------- K0: R_eff[ne][j] folded router matrix (fp64) ----------------
// R_eff[n*8+e][j] = sum_d in_w[(n*128+d)*1024 + j] * router_w[ne*128 + d]
// Stored transposed: Rt[j*64 + ne] for coalesced reads in the router kernel.
__global__ __launch_bounds__(256) void reff_kernel(
    const float* __restrict__ in_w, const float* __restrict__ in_b,
    const float* __restrict__ router_w, double* __restrict__ Rt, double* __restrict__ lb)
{
  const int ne = blockIdx.x;       // 0..63
  const int n  = ne >> 3;
  __shared__ double rw[DH];
  for (int d = threadIdx.x; d < DH; d += 256) rw[d] = (double)router_w[ne*DH + d];
  __syncthreads();
  for (int j = threadIdx.x; j < DMODEL; j += 256) {
    double acc = 0.0;
    #pragma unroll 4
    for (int d = 0; d < DH; ++d)
      acc += (double)in_w[(size_t)(n*DH + d)*DMODEL + j] * rw[d];
    Rt[(size_t)j*NNE + ne] = acc;
  }
  if (threadIdx.x == 0) {
    double acc = 0.0;
    for (int d = 0; d < DH; ++d) acc += (double)in_b[n*DH + d] * rw[d];
    lb[ne] = acc;  // logit bias (in_b is zeros, but keep general)
  }
}

// ---------------- K1: fp64 logits + top-2 + softmax + bucket scatter ----------------
// 8 tokens per block. thread = (slot 0..3) x (ne 0..63); each thread does 2 tokens.
__global__ __launch_bounds__(256) void router_kernel(
    const float* __restrict__ x, const double* __restrict__ Rt, const double* __restrict__ lb,
    int* __restrict__ counts, int* __restrict__ lists, float* __restrict__ lw)
{
  const int tok0 = blockIdx.x * 8;
  __shared__ float  xs[8][DMODEL];   // 32 KB
  __shared__ double lg[8][NNE];      // 4 KB
  for (int idx = threadIdx.x; idx < 8*(DMODEL/4); idx += 256) {
    const int r = idx >> 8;
    const int c = (idx & 255) << 2;
    *(float4*)&xs[r][c] = *(const float4*)(x + (size_t)(tok0 + r)*DMODEL + c);
  }
  __syncthreads();
  const int ne = threadIdx.x & 63;
  const int slot = threadIdx.x >> 6;   // 0..3; wave-uniform -> xs reads broadcast
  double a0 = lb[ne], a1 = lb[ne];
  #pragma unroll 2
  for (int j = 0; j < DMODEL; ++j) {
    const double r = Rt[(size_t)j*NNE + ne];   // lanes = consecutive ne: coalesced 512B
    a0 += r * (double)xs[slot][j];
    a1 += r * (double)xs[slot + 4][j];
  }
  lg[slot][ne] = a0; lg[slot + 4][ne] = a1;
  __syncthreads();
  if (threadIdx.x < 64) {
    const int t = threadIdx.x >> 3;
    const int n = threadIdx.x & 7;
    const double* l = &lg[t][n*NEXP];
    int e1 = 0; double v1 = l[0];
    #pragma unroll
    for (int e = 1; e < NEXP; ++e) if (l[e] > v1) { v1 = l[e]; e1 = e; }   // ties -> lower idx (top_k semantics)
    int e2 = -1; double v2 = -1.0e300;
    #pragma unroll
    for (int e = 0; e < NEXP; ++e) if (e != e1 && l[e] > v2) { v2 = l[e]; e2 = e; }
    const double ed = exp(v2 - v1);              // <= 1, stable
    const float w1 = (float)(1.0 / (1.0 + ed));
    const float w2 = (float)(ed / (1.0 + ed));
    const int tok = tok0 + t;
    const int b1 = n*NEXP + e1, b2 = n*NEXP + e2;
    const int p1 = atomicAdd(&counts[b1], 1);
    lists[(size_t)b1*T_TOK + p1] = tok; lw[(size_t)b1*T_TOK + p1] = w1;
    const int p2 = atomicAdd(&counts[b2], 1);
    lists[(size_t)b2*T_TOK + p2] = tok; lw[(size_t)b2*T_TOK + p2] = w2;
  }
}

// ---------------- sgemm: C[M][N] = A[M][K] * B[N][K]^T + bias[N]  (fp32) ----------------
// BM=BN=128, BK=16, 256 threads, 8x8 micro-tile.
__global__ __launch_bounds__(256) void sgemm_bt(
    const float* __restrict__ A, const float* __restrict__ B,
    const float* __restrict__ bias, float* __restrict__ C,
    const int M, const int N, const int K)
{
  __shared__ float As[16][132];
  __shared__ float Bs[16][132];
  const int tid = threadIdx.x;
  const int bm = blockIdx.y << 7, bn = blockIdx.x << 7;
  const int row = tid >> 1;            // 0..127
  const int kq  = (tid & 1) << 3;      // 0 or 8
  const int m0 = (tid & 15) << 3;
  const int n0 = (tid >> 4) << 3;
  const float* gA = A + (size_t)(bm + row)*K + kq;
  const float* gB = B + (size_t)(bn + row)*K + kq;
  float acc[8][8] = {};
  for (int k0 = 0; k0 < K; k0 += 16) {
    const float4 a0 = *(const float4*)(gA + k0);
    const float4 a1 = *(const float4*)(gA + k0 + 4);
    const float4 b0 = *(const float4*)(gB + k0);
    const float4 b1 = *(const float4*)(gB + k0 + 4);
    __syncthreads();
    As[kq+0][row]=a0.x; As[kq+1][row]=a0.y; As[kq+2][row]=a0.z; As[kq+3][row]=a0.w;
    As[kq+4][row]=a1.x; As[kq+5][row]=a1.y; As[kq+6][row]=a1.z; As[kq+7][row]=a1.w;
    Bs[kq+0][row]=b0.x; Bs[kq+1][row]=b0.y; Bs[kq+2][row]=b0.z; Bs[kq+3][row]=b0.w;
    Bs[kq+4][row]=b1.x; Bs[kq+5][row]=b1.y; Bs[kq+6][row]=b1.z; Bs[kq+7][row]=b1.w;
    __syncthreads();
    #pragma unroll
    for (int k = 0; k < 16; ++k) {
      const float4 av0 = *(const float4*)&As[k][m0];
      const float4 av1 = *(const float4*)&As[k][m0+4];
      const float4 bv0 = *(const float4*)&Bs[k][n0];
      const float4 bv1 = *(const float4*)&Bs[k][n0+4];
      const float a[8] = {av0.x,av0.y,av0.z,av0.w,av1.x,av1.y,av1.z,av1.w};
      const float b[8] = {bv0.x,bv0.y,bv0.z,bv0.w,bv1.x,bv1.y,bv1.z,bv1.w};
      #pragma unroll
      for (int i = 0; i < 8; ++i)
        #pragma unroll
        for (int j = 0; j < 8; ++j)
          acc[i][j] += a[i]*b[j];
    }
  }
  float bv[8];
  #pragma unroll
  for (int j = 0; j < 8; ++j) bv[j] = bias[bn + n0 + j];
  #pragma unroll
  for (int i = 0; i < 8; ++i) {
    float4 o0, o1;
    o0.x=acc[i][0]+bv[0]; o0.y=acc[i][1]+bv[1]; o0.z=acc[i][2]+bv[2]; o0.w=acc[i][3]+bv[3];
    o1.x=acc[i][4]+bv[4]; o1.y=acc[i][5]+bv[5]; o1.z=acc[i][6]+bv[6]; o1.w=acc[i][7]+bv[7];
    float* cp = C + (size_t)(bm + m0 + i)*N + bn + n0;
    *(float4*)cp = o0;
    *(float4*)(cp + 4) = o1;
  }
}

// ---------------- K3: fused expert FFN over bucketed tokens ----------------
// block = one (head,expert) bucket x 64-token tile.
// ye[t][:] = (gelu(h_row . W_in^T) . W_out) * gate_w  -> atomicAdd into y.
__global__ __launch_bounds__(256) void ffn_kernel(
    const float* __restrict__ h, const float* __restrict__ w_in, const float* __restrict__ w_out,
    const int* __restrict__ counts, const int* __restrict__ lists, const float* __restrict__ lw,
    float* __restrict__ y)
{
  const int ne = blockIdx.x;         // 0..63
  const int n  = ne >> 3;
  const int cnt = counts[ne];
  const int t0 = blockIdx.y * 64;
  if (t0 >= cnt) return;
  const int nt = min(64, cnt - t0);

  __shared__ float hs[64][DH + 4];     // 33.8 KB, [token][d]
  __shared__ float ws[32][DH + 4];     // 16.9 KB, w_in chunk [f][d]
  __shared__ float hidT[32][66];       //  8.4 KB, [f][token]
  __shared__ float lwv[64];
  __shared__ int   tokv[64];

  const int tid = threadIdx.x;
  if (tid < 64) {
    int tok = 0; float w = 0.f;
    if (tid < nt) {
      tok = lists[(size_t)ne*T_TOK + t0 + tid];
      w   = lw[(size_t)ne*T_TOK + t0 + tid];
    }
    tokv[tid] = tok; lwv[tid] = w;
  }
  __syncthreads();
  for (int idx = tid; idx < 64*(DH/4); idx += 256) {
    const int r = idx >> 5;
    const int c = (idx & 31) << 2;
    float4 v = make_float4(0.f,0.f,0.f,0.f);
    if (r < nt) v = *(const float4*)(h + (size_t)tokv[r]*DMODEL + n*DH + c);
    *(float4*)&hs[r][c] = v;
  }

  const int tlane = tid & 15;          // tokens tlane + 16*i (strided micro -> 2-way LDS)
  const int fr0   = (tid >> 4) << 1;   // phase1: 2 f-rows
  const int dcol0 = (tid >> 4) << 3;   // phase2: 8 d-cols

  float ye[4][8] = {};
  const float* winB  = w_in  + (size_t)ne*DHID*DH;
  const float* woutB = w_out + (size_t)ne*DHID*DH;

  for (int fc = 0; fc < DHID; fc += 32) {
    __syncthreads();   // prev iteration done with ws/hidT
    for (int idx = tid; idx < 32*(DH/4); idx += 256) {
      const int f = idx >> 5;
      const int c = (idx & 31) << 2;
      *(float4*)&ws[f][c] = *(const float4*)(winB + (size_t)(fc + f)*DH + c);
    }
    __syncthreads();
    // phase 1: hidT[f][t] = gelu( hs[t][:] . ws[f][:] )
    {
      float acc1[2][4] = {};
      #pragma unroll 2
      for (int d = 0; d < DH; d += 4) {
        const float4 w0 = *(const float4*)&ws[fr0][d];
        const float4 w1 = *(const float4*)&ws[fr0+1][d];
        const float4 h0 = *(const float4*)&hs[tlane     ][d];
        const float4 h1 = *(const float4*)&hs[tlane + 16][d];
        const float4 h2 = *(const float4*)&hs[tlane + 32][d];
        const float4 h3 = *(const float4*)&hs[tlane + 48][d];
        acc1[0][0] += w0.x*h0.x + w0.y*h0.y + w0.z*h0.z + w0.w*h0.w;
        acc1[0][1] += w0.x*h1.x + w0.y*h1.y + w0.z*h1.z + w0.w*h1.w;
        acc1[0][2] += w0.x*h2.x + w0.y*h2.y + w0.z*h2.z + w0.w*h2.w;
        acc1[0][3] += w0.x*h3.x + w0.y*h3.y + w0.z*h3.z + w0.w*h3.w;
        acc1[1][0] += w1.x*h0.x + w1.y*h0.y + w1.z*h0.z + w1.w*h0.w;
        acc1[1][1] += w1.x*h1.x + w1.y*h1.y + w1.z*h1.z + w1.w*h1.w;
        acc1[1][2] += w1.x*h2.x + w1.y*h2.y + w1.z*h2.z + w1.w*h2.w;
        acc1[1][3] += w1.x*h3.x + w1.y*h3.y + w1.z*h3.z + w1.w*h3.w;
      }
      #pragma unroll
      for (int fi = 0; fi < 2; ++fi)
        #pragma unroll
        for (int ti = 0; ti < 4; ++ti) {
          const float v = acc1[fi][ti];
          const float g = 0.5f * v * (1.0f + erff(v * 0.70710678118654752f));  // exact-erf gelu
          hidT[fr0 + fi][tlane + 16*ti] = g;
        }
    }
    __syncthreads();
    // phase 2: ye[t][d] += hidT[f][t] * w_out[f][d]   (w_out via L1/L2, broadcast across lanes)
    #pragma unroll 4
    for (int f = 0; f < 32; ++f) {
      const float4 wo0 = *(const float4*)(woutB + (size_t)(fc + f)*DH + dcol0);
      const float4 wo1 = *(const float4*)(woutB + (size_t)(fc + f)*DH + dcol0 + 4);
      const float s0 = hidT[f][tlane     ];
      const float s1 = hidT[f][tlane + 16];
      const float s2 = hidT[f][tlane + 32];
      const float s3 = hidT[f][tlane + 48];
      ye[0][0]+=s0*wo0.x; ye[0][1]+=s0*wo0.y; ye[0][2]+=s0*wo0.z; ye[0][3]+=s0*wo0.w;
      ye[0][4]+=s0*wo1.x; ye[0][5]+=s0*wo1.y; ye[0][6]+=s0*wo1.z; ye[0][7]+=s0*wo1.w;
      ye[1][0]+=s1*wo0.x; ye[1][1]+=s1*wo0.y; ye[1][2]+=s1*wo0.z; ye[1][3]+=s1*wo0.w;
      ye[1][4]+=s1*wo1.x; ye[1][5]+=s1*wo1.y; ye[1][6]+=s1*wo1.z; ye[1][7]+=s1*wo1.w;
      ye[2][0]+=s2*wo0.x; ye[2][1]+=s2*wo0.y; ye[2][2]+=s2*wo0.z; ye[2][3]+=s2*wo0.w;
      ye[2][4]+=s2*wo1.x; ye[2][5]+=s2*wo1.y; ye[2][6]+=s2*wo1.z; ye[2][7]+=s2*wo1.w;
      ye[3][0]+=s3*wo0.x; ye[3][1]+=s3*wo0.y; ye[3][2]+=s3*wo0.z; ye[3][3]+=s3*wo0.w;
      ye[3][4]+=s3*wo1.x; ye[3][5]+=s3*wo1.y; ye[3][6]+=s3*wo1.z; ye[3][7]+=s3*wo1.w;
    }
  }
  // epilogue: exactly 2 atomicAdds per y element across the whole grid -> deterministic (add is commutative)
  #pragma unroll
  for (int ti = 0; ti < 4; ++ti) {
    const int t = tlane + 16*ti;
    if (t < nt) {
      const float w = lwv[t];
      float* yp = y + (size_t)tokv[t]*DMODEL + n*DH + dcol0;
      #pragma unroll
      for (int j = 0; j < 8; ++j) atomicAdd(yp + j, w * ye[ti][j]);
    }
  }
}

// ---------------- launch ----------------
extern "C" void kernel_launch(void* const* d_in, const int* in_sizes, int n_in,
                              void* d_out, int out_size, void* d_ws, size_t ws_size,
                              hipStream_t stream) {
  const float* x        = (const float*)d_in[0];
  const float* in_w     = (const float*)d_in[1];
  const float* in_b     = (const float*)d_in[2];
  const float* router_w = (const float*)d_in[3];
  const float* w_in     = (const float*)d_in[4];
  const float* w_out    = (const float*)d_in[5];
  const float* out_w    = (const float*)d_in[6];
  const float* out_b    = (const float*)d_in[7];
  float* out = (float*)d_out;

  size_t off = 0;
  char* base = (char*)d_ws;
  auto alloc = [&](size_t bytes) -> void* {
    void* p = base + off;
    off += (bytes + 255) & ~(size_t)255;
    return p;
  };
  float*  h      = (float*) alloc((size_t)T_TOK*DMODEL*sizeof(float));   // 33.6 MB
  float*  y      = (float*) alloc((size_t)T_TOK*DMODEL*sizeof(float));   // 33.6 MB
  double* Rt     = (double*)alloc((size_t)DMODEL*NNE*sizeof(double));    // 0.5 MB
  double* lb     = (double*)alloc(NNE*sizeof(double));
  int*    counts = (int*)   alloc(NNE*sizeof(int));
  int*    lists  = (int*)   alloc((size_t)NNE*T_TOK*sizeof(int));        // 2 MB
  float*  lwp    = (float*) alloc((size_t)NNE*T_TOK*sizeof(float));      // 2 MB
  // total ~72 MB of workspace

  hipMemsetAsync(counts, 0, NNE*sizeof(int), stream);
  hipMemsetAsync(y, 0, (size_t)T_TOK*DMODEL*sizeof(float), stream);

  reff_kernel  <<<NNE, 256, 0, stream>>>(in_w, in_b, router_w, Rt, lb);
  router_kernel<<<T_TOK/8, 256, 0, stream>>>(x, Rt, lb, counts, lists, lwp);
  sgemm_bt     <<<dim3(DMODEL/128, T_TOK/128), 256, 0, stream>>>(x, in_w, in_b, h, T_TOK, DMODEL, DMODEL);
  ffn_kernel   <<<dim3(NNE, T_TOK/64), 256, 0, stream>>>(h, w_in, w_out, counts, lists, lwp, y);
  sgemm_bt     <<<dim3(DMODEL/128, T_TOK/128), 256, 0, stream>>>(y, out_w, out_b, out, T_TOK, DMODEL, DMODEL);
}

// Round 2
// 599.360 us; speedup vs baseline: 2.8775x; 2.8775x over previous
//
#include <hip/hip_runtime.h>
#include <hip/hip_bf16.h>
#include <cmath>

#define T_TOK 8192
#define DMODEL 1024
#define NHEAD 8
#define DH 128
#define NEXP 8
#define NNE 64      // NHEAD*NEXP
#define DHID 512

typedef __bf16 bf16x8 __attribute__((ext_vector_type(8)));
typedef float f32x4 __attribute__((ext_vector_type(4)));
typedef unsigned short u16x8 __attribute__((ext_vector_type(8)));

#define GLDS16(g, l) __builtin_amdgcn_global_load_lds( \
    (const __attribute__((address_space(1))) unsigned int*)(g), \
    (__attribute__((address_space(3))) unsigned int*)(l), 16, 0, 0)

static __device__ inline unsigned short f2bf(float f) {
  return __builtin_bit_cast(unsigned short, __float2bfloat16(f));
}
static __device__ inline float bf2f(unsigned short u) {
  unsigned int v = ((unsigned int)u) << 16;
  return __builtin_bit_cast(float, v);
}

// ---------------- fp32 -> bf16 bulk convert ----------------
__global__ __launch_bounds__(256) void cvt_bf16_kernel(
    const float* __restrict__ src, unsigned short* __restrict__ dst, int n8)
{
  int i = blockIdx.x*256 + threadIdx.x;
  const int stride = gridDim.x*256;
  for (; i < n8; i += stride) {
    const float4 a = *((const float4*)src + (size_t)i*2);
    const float4 b = *((const float4*)src + (size_t)i*2 + 1);
    u16x8 v;
    v[0]=f2bf(a.x); v[1]=f2bf(a.y); v[2]=f2bf(a.z); v[3]=f2bf(a.w);
    v[4]=f2bf(b.x); v[5]=f2bf(b.y); v[6]=f2bf(b.z); v[7]=f2bf(b.w);
    *((u16x8*)dst + i) = v;
  }
}

// ---------------- w_out [ne][f][d] fp32 -> w_outT [ne][d][f] bf16 ----------------
__global__ __launch_bounds__(256) void wout_transpose_kernel(
    const float* __restrict__ w_out, unsigned short* __restrict__ woutT)
{
  const int ne = blockIdx.x;
  const float* src = w_out + (size_t)ne*DHID*DH;
  unsigned short* dst = woutT + (size_t)ne*DH*DHID;
  __shared__ float ws[32][DH+4];
  for (int fc = 0; fc < DHID; fc += 32) {
    __syncthreads();
    for (int i = threadIdx.x; i < 32*DH; i += 256) {
      const int f = i >> 7, d = i & 127;
      ws[f][d] = src[(size_t)(fc+f)*DH + d];
    }
    __syncthreads();
    for (int i = threadIdx.x; i < 32*DH; i += 256) {
      const int d = i >> 5, f = i & 31;
      dst[(size_t)d*DHID + fc + f] = f2bf(ws[f][d]);
    }
  }
}

// ---------------- K0: folded router matrix (fp64) ----------------
__global__ __launch_bounds__(256) void reff_kernel(
    const float* __restrict__ in_w, const float* __restrict__ in_b,
    const float* __restrict__ router_w, double* __restrict__ Rt, double* __restrict__ lb)
{
  const int ne = blockIdx.x;
  const int n  = ne >> 3;
  __shared__ double rw[DH];
  for (int d = threadIdx.x; d < DH; d += 256) rw[d] = (double)router_w[ne*DH + d];
  __syncthreads();
  for (int j = threadIdx.x; j < DMODEL; j += 256) {
    double acc = 0.0;
    #pragma unroll 4
    for (int d = 0; d < DH; ++d)
      acc += (double)in_w[(size_t)(n*DH + d)*DMODEL + j] * rw[d];
    Rt[(size_t)j*NNE + ne] = acc;
  }
  if (threadIdx.x == 0) {
    double acc = 0.0;
    for (int d = 0; d < DH; ++d) acc += (double)in_b[n*DH + d] * rw[d];
    lb[ne] = acc;
  }
}

// ---------------- K1: fp64 logits + top-2 + softmax + bucket scatter ----------------
__global__ __launch_bounds__(256) void router_kernel(
    const float* __restrict__ x, const double* __restrict__ Rt, const double* __restrict__ lb,
    int* __restrict__ counts, int* __restrict__ lists, float* __restrict__ wbuf)
{
  const int tok0 = blockIdx.x * 8;
  __shared__ float  xs[8][DMODEL];
  __shared__ double lg[8][NNE];
  for (int idx = threadIdx.x; idx < 8*(DMODEL/4); idx += 256) {
    const int r = idx >> 8;
    const int c = (idx & 255) << 2;
    *(float4*)&xs[r][c] = *(const float4*)(x + (size_t)(tok0 + r)*DMODEL + c);
  }
  __syncthreads();
  const int ne = threadIdx.x & 63;
  const int slot = threadIdx.x >> 6;
  double a0 = lb[ne], a1 = lb[ne];
  #pragma unroll 2
  for (int j = 0; j < DMODEL; ++j) {
    const double r = Rt[(size_t)j*NNE + ne];
    a0 += r * (double)xs[slot][j];
    a1 += r * (double)xs[slot + 4][j];
  }
  lg[slot][ne] = a0; lg[slot + 4][ne] = a1;
  __syncthreads();
  if (threadIdx.x < 64) {
    const int t = threadIdx.x >> 3;
    const int n = threadIdx.x & 7;
    const double* l = &lg[t][n*NEXP];
    int e1 = 0; double v1 = l[0];
    #pragma unroll
    for (int e = 1; e < NEXP; ++e) if (l[e] > v1) { v1 = l[e]; e1 = e; }
    int e2 = -1; double v2 = -1.0e300;
    #pragma unroll
    for (int e = 0; e < NEXP; ++e) if (e != e1 && l[e] > v2) { v2 = l[e]; e2 = e; }
    const double ed = exp(v2 - v1);
    const float w1 = (float)(1.0 / (1.0 + ed));
    const float w2 = (float)(ed / (1.0 + ed));
    const int tok = tok0 + t;
    const int b1 = n*NEXP + e1, b2 = n*NEXP + e2;
    const int p1 = atomicAdd(&counts[b1], 1);
    lists[(size_t)b1*T_TOK + p1] = tok*2;        // slot 0
    const int p2 = atomicAdd(&counts[b2], 1);
    lists[(size_t)b2*T_TOK + p2] = tok*2 + 1;    // slot 1
    wbuf[(size_t)(tok*NHEAD + n)*2 + 0] = w1;
    wbuf[(size_t)(tok*NHEAD + n)*2 + 1] = w2;
  }
}

// ---------------- dense GEMM: C[M][N] = A[M][K] * B[N][K]^T + bias, bf16 MFMA ----------------
// m97 structure: 128x128 tile, BK=32, 4 waves (each 64x64), global_load_lds staging.
template<bool BF16OUT>
__global__ __launch_bounds__(256) void gemm_bf16(
    const unsigned short* __restrict__ A, const unsigned short* __restrict__ B,
    const float* __restrict__ bias, void* __restrict__ Cv,
    const int M, const int N, const int K)
{
  __shared__ __align__(16) unsigned short As[128*32];
  __shared__ __align__(16) unsigned short Bs[128*32];
  const int t = threadIdx.x;
  const int lane = t & 63, w = t >> 6;
  const int bm = blockIdx.y << 7, bn = blockIdx.x << 7;
  const int wm = (w & 1) << 6, wn = (w >> 1) << 6;
  f32x4 acc[4][4];
  #pragma unroll
  for (int i = 0; i < 4; ++i)
    #pragma unroll
    for (int j = 0; j < 4; ++j)
      acc[i][j] = (f32x4){0.f, 0.f, 0.f, 0.f};

  const int srow = t >> 2;
  const int skb = (t & 3) << 3;   // k element offset for staging
  const unsigned short* gA = A + (size_t)(bm + srow)*K + skb;
  const unsigned short* gB = B + (size_t)(bn + srow)*K + skb;
  const size_t rowK64 = (size_t)64*K;
  char* lA = (char*)As + t*16;
  char* lB = (char*)Bs + t*16;
  const int rlo = lane & 15;
  const int khi = (lane >> 4) << 4;   // byte offset of 8-elem k-group

  for (int k0 = 0; k0 < K; k0 += 32) {
    GLDS16(gA + k0,          lA);
    GLDS16(gA + rowK64 + k0, lA + 4096);
    GLDS16(gB + k0,          lB);
    GLDS16(gB + rowK64 + k0, lB + 4096);
    __syncthreads();
    bf16x8 av[4], bv[4];
    #pragma unroll
    for (int i = 0; i < 4; ++i) {
      av[i] = *(const bf16x8*)((const char*)As + (wm + i*16 + rlo)*64 + khi);
      bv[i] = *(const bf16x8*)((const char*)Bs + (wn + i*16 + rlo)*64 + khi);
    }
    #pragma unroll
    for (int i = 0; i < 4; ++i)
      #pragma unroll
      for (int j = 0; j < 4; ++j)
        acc[i][j] = __builtin_amdgcn_mfma_f32_16x16x32_bf16(av[i], bv[j], acc[i][j], 0, 0, 0);
    __syncthreads();
  }
  const int rq = (lane >> 4) << 2;
  #pragma unroll
  for (int j = 0; j < 4; ++j) {
    const int col = bn + wn + j*16 + rlo;
    const float bb = bias[col];
    #pragma unroll
    for (int i = 0; i < 4; ++i) {
      const int row0 = bm + wm + i*16 + rq;
      #pragma unroll
      for (int r = 0; r < 4; ++r) {
        const float v = acc[i][j][r] + bb;
        if (BF16OUT) ((unsigned short*)Cv)[(size_t)(row0 + r)*N + col] = f2bf(v);
        else         ((float*)Cv)[(size_t)(row0 + r)*N + col] = v;
      }
    }
  }
}

// ---------------- K3: fused expert FFN, bf16 MFMA, bucketed tokens ----------------
// block = (bucket ne, 128-token tile), 4 waves. XOR-swizzled LDS everywhere.
__global__ __launch_bounds__(256) void ffn_mfma_kernel(
    const unsigned short* __restrict__ h_bf, const unsigned short* __restrict__ win_bf,
    const unsigned short* __restrict__ woutT_bf, const int* __restrict__ counts,
    const int* __restrict__ lists, unsigned short* __restrict__ ye_buf)
{
  const int ne = blockIdx.x;
  const int n  = ne >> 3;
  const int cnt = counts[ne];
  const int t0 = blockIdx.y << 7;
  if (t0 >= cnt) return;
  const int nt = min(128, cnt - t0);

  __shared__ __align__(16) unsigned short hA[128*128];    // 32 KB, rows 256B, swizzled
  __shared__ __align__(16) unsigned short wInS[64*128];   // 16 KB, rows 256B, swizzled
  __shared__ __align__(16) unsigned short wOutS[128*64];  // 16 KB, rows 128B, swizzled
  __shared__ __align__(16) unsigned short hidS[128*64];   // 16 KB, rows 128B, swizzled

  const int t = threadIdx.x;
  const int lane = t & 63, w = t >> 6;
  const long lbase = (long)ne * T_TOK;

  // gather token rows of h into hA (per-lane global addr carries the inverse swizzle)
  #pragma unroll
  for (int s = 0; s < 8; ++s) {
    const int o = s*4096 + t*16;
    const int row = o >> 8;
    const int c = (t & 15) ^ (row & 7);
    const int trow = t0 + row;
    const int ts = lists[lbase + (trow < cnt ? trow : t0)];
    const unsigned short* g = h_bf + (size_t)(ts >> 1)*DMODEL + n*DH + c*8;
    GLDS16(g, (char*)hA + o);
  }

  const unsigned short* winB  = win_bf  + (size_t)ne*DHID*DH;
  const unsigned short* woutB = woutT_bf + (size_t)ne*DH*DHID;

  const int wm = (w & 1) << 6;   // token quadrant base
  const int wf = (w >> 1) << 5;  // f base (gemm1)
  const int wd = (w >> 1) << 6;  // d base (gemm2)
  const int rlo = lane & 15;
  const int kq  = lane >> 4;     // 0..3

  f32x4 acc2[4][4];
  #pragma unroll
  for (int i = 0; i < 4; ++i)
    #pragma unroll
    for (int j = 0; j < 4; ++j)
      acc2[i][j] = (f32x4){0.f, 0.f, 0.f, 0.f};

  for (int fc = 0; fc < DHID; fc += 64) {
    // stage wIn chunk [64][128] + wOut chunk [128][64]
    #pragma unroll
    for (int s = 0; s < 4; ++s) {
      const int o = s*4096 + t*16;
      const int row = o >> 8;                     // 0..63
      const int c = (t & 15) ^ (row & 7);
      GLDS16(winB + (size_t)(fc + row)*DH + c*8, (char*)wInS + o);
    }
    #pragma unroll
    for (int s = 0; s < 4; ++s) {
      const int o = s*4096 + t*16;
      const int row = o >> 7;                     // 0..127
      const int c = (t & 7) ^ (row & 7);
      GLDS16(woutB + (size_t)row*DHID + fc + c*8, (char*)wOutS + o);
    }
    __syncthreads();   // (A) staged data visible

    // GEMM1: hid[t][f] = hA @ wIn^T ; this wave: tokens wm..+63, f wf..+31
    f32x4 acc1[4][2];
    #pragma unroll
    for (int i = 0; i < 4; ++i) {
      acc1[i][0] = (f32x4){0.f,0.f,0.f,0.f};
      acc1[i][1] = (f32x4){0.f,0.f,0.f,0.f};
    }
    #pragma unroll
    for (int ks = 0; ks < 4; ++ks) {
      const int kb = ks*64 + kq*16;
      bf16x8 a[4], b[2];
      #pragma unroll
      for (int i = 0; i < 4; ++i) {
        const int tr = wm + i*16 + rlo;
        a[i] = *(const bf16x8*)((const char*)hA + tr*256 + (kb ^ ((tr & 7) << 4)));
      }
      #pragma unroll
      for (int j = 0; j < 2; ++j) {
        const int fr = wf + j*16 + rlo;
        b[j] = *(const bf16x8*)((const char*)wInS + fr*256 + (kb ^ ((fr & 7) << 4)));
      }
      #pragma unroll
      for (int i = 0; i < 4; ++i)
        #pragma unroll
        for (int j = 0; j < 2; ++j)
          acc1[i][j] = __builtin_amdgcn_mfma_f32_16x16x32_bf16(a[i], b[j], acc1[i][j], 0, 0, 0);
    }
    // exact-erf gelu, cvt bf16, write hid chunk (swizzled)
    #pragma unroll
    for (int i = 0; i < 4; ++i)
      #pragma unroll
      for (int j = 0; j < 2; ++j)
        #pragma unroll
        for (int r = 0; r < 4; ++r) {
          const float v = acc1[i][j][r];
          const float g = 0.5f * v * (1.0f + erff(v * 0.70710678118654752f));
          const int tr = wm + i*16 + kq*4 + r;
          const int f  = wf + j*16 + rlo;
          const int byte = tr*128 + (((f >> 3) ^ (tr & 7)) << 4) + ((f & 7) << 1);
          *(unsigned short*)((char*)hidS + byte) = f2bf(g);
        }
    __syncthreads();   // (B) hid visible; wIn reads done

    // GEMM2: ye += hid_chunk @ wOut_chunk^T ; this wave: tokens wm..+63, d wd..+63
    #pragma unroll
    for (int ks = 0; ks < 2; ++ks) {
      const int kb = ks*64 + kq*16;
      bf16x8 a[4], b[4];
      #pragma unroll
      for (int i = 0; i < 4; ++i) {
        const int tr = wm + i*16 + rlo;
        a[i] = *(const bf16x8*)((const char*)hidS + tr*128 + (kb ^ ((tr & 7) << 4)));
      }
      #pragma unroll
      for (int j = 0; j < 4; ++j) {
        const int dr = wd + j*16 + rlo;
        b[j] = *(const bf16x8*)((const char*)wOutS + dr*128 + (kb ^ ((dr & 7) << 4)));
      }
      #pragma unroll
      for (int i = 0; i < 4; ++i)
        #pragma unroll
        for (int j = 0; j < 4; ++j)
          acc2[i][j] = __builtin_amdgcn_mfma_f32_16x16x32_bf16(a[i], b[j], acc2[i][j], 0, 0, 0);
    }
    __syncthreads();   // (C) hid/wOut reads done -> next stage safe
  }

  // epilogue: scatter ye rows (bf16) to per-(tok,head,slot) buffer — no atomics
  #pragma unroll
  for (int i = 0; i < 4; ++i) {
    #pragma unroll
    for (int r = 0; r < 4; ++r) {
      const int tr = wm + i*16 + kq*4 + r;
      if (tr < nt) {
        const int ts = lists[lbase + t0 + tr];
        unsigned short* dst = ye_buf +
            ((((size_t)(ts >> 1))*NHEAD + n)*2 + (ts & 1))*DH + wd;
        #pragma unroll
        for (int j = 0; j < 4; ++j)
          dst[j*16 + rlo] = f2bf(acc2[i][j][r]);
      }
    }
  }
}

// ---------------- K4: gate-weighted combine of the two slots -> y (bf16) ----------------
__global__ __launch_bounds__(256) void combine_kernel(
    const unsigned short* __restrict__ ye_buf, const float* __restrict__ wbuf,
    unsigned short* __restrict__ y_bf)
{
  const int u = blockIdx.x*256 + threadIdx.x;   // 0 .. T*NH*16 - 1
  const int tn = u >> 4;        // t*NHEAD + n
  const int ch = u & 15;        // 8-elem chunk within DH
  const float w0 = wbuf[(size_t)tn*2 + 0];
  const float w1 = wbuf[(size_t)tn*2 + 1];
  const u16x8 a = *((const u16x8*)ye_buf + (size_t)tn*32 + ch);
  const u16x8 b = *((const u16x8*)ye_buf + (size_t)tn*32 + 16 + ch);
  u16x8 v;
  #pragma unroll
  for (int j = 0; j < 8; ++j)
    v[j] = f2bf(w0*bf2f(a[j]) + w1*bf2f(b[j]));
  *((u16x8*)y_bf + u) = v;
}

// ---------------- launch ----------------
extern "C" void kernel_launch(void* const* d_in, const int* in_sizes, int n_in,
                              void* d_out, int out_size, void* d_ws, size_t ws_size,
                              hipStream_t stream) {
  const float* x        = (const float*)d_in[0];
  const float* in_w     = (const float*)d_in[1];
  const float* in_b     = (const float*)d_in[2];
  const float* router_w = (const float*)d_in[3];
  const float* w_in     = (const float*)d_in[4];
  const float* w_out    = (const float*)d_in[5];
  const float* out_w    = (const float*)d_in[6];
  const float* out_b    = (const float*)d_in[7];
  float* out = (float*)d_out;

  size_t off = 0;
  char* base = (char*)d_ws;
  auto alloc = [&](size_t bytes) -> void* {
    void* p = base + off;
    off += (bytes + 255) & ~(size_t)255;
    return p;
  };
  unsigned short* h_bf    = (unsigned short*)alloc((size_t)T_TOK*DMODEL*2);      // 16.8 MB
  unsigned short* x_bf    = (unsigned short*)alloc((size_t)T_TOK*DMODEL*2);      // 16.8 MB (reused as y_bf)
  unsigned short* inw_bf  = (unsigned short*)alloc((size_t)DMODEL*DMODEL*2);     //  2.1 MB
  unsigned short* outw_bf = (unsigned short*)alloc((size_t)DMODEL*DMODEL*2);     //  2.1 MB
  unsigned short* win_bf  = (unsigned short*)alloc((size_t)NNE*DHID*DH*2);       //  8.4 MB
  unsigned short* woutT_bf= (unsigned short*)alloc((size_t)NNE*DH*DHID*2);       //  8.4 MB
  unsigned short* ye_buf  = (unsigned short*)alloc((size_t)T_TOK*NHEAD*2*DH*2);  // 33.6 MB
  float*  wbuf   = (float*) alloc((size_t)T_TOK*NHEAD*2*4);                      //  0.5 MB
  double* Rt     = (double*)alloc((size_t)DMODEL*NNE*8);
  double* lb     = (double*)alloc(NNE*8);
  int*    counts = (int*)   alloc(NNE*4);
  int*    lists  = (int*)   alloc((size_t)NNE*T_TOK*4);                          //  2.0 MB
  unsigned short* y_bf = x_bf;  // x_bf dead after gemm1; combine runs later

  hipMemsetAsync(counts, 0, NNE*4, stream);

  // dtype prep
  cvt_bf16_kernel<<<2048, 256, 0, stream>>>(x,     x_bf,    T_TOK*DMODEL/8);
  cvt_bf16_kernel<<<512,  256, 0, stream>>>(in_w,  inw_bf,  DMODEL*DMODEL/8);
  cvt_bf16_kernel<<<512,  256, 0, stream>>>(out_w, outw_bf, DMODEL*DMODEL/8);
  cvt_bf16_kernel<<<2048, 256, 0, stream>>>(w_in,  win_bf,  NNE*DHID*DH/8);
  wout_transpose_kernel<<<NNE, 256, 0, stream>>>(w_out, woutT_bf);

  // router (fp64 path, reads original fp32 inputs — selection-exact)
  reff_kernel  <<<NNE, 256, 0, stream>>>(in_w, in_b, router_w, Rt, lb);
  router_kernel<<<T_TOK/8, 256, 0, stream>>>(x, Rt, lb, counts, lists, wbuf);

  // h = x @ in_w^T + in_b   (bf16 out)
  gemm_bf16<true><<<dim3(DMODEL/128, T_TOK/128), 256, 0, stream>>>(
      x_bf, inw_bf, in_b, h_bf, T_TOK, DMODEL, DMODEL);

  // expert FFN (top-2 sparse) -> ye_buf
  ffn_mfma_kernel<<<dim3(NNE, T_TOK/128), 256, 0, stream>>>(
      h_bf, win_bf, woutT_bf, counts, lists, ye_buf);

  // y = w0*ye0 + w1*ye1  (bf16)
  combine_kernel<<<T_TOK*NHEAD*16/256, 256, 0, stream>>>(ye_buf, wbuf, y_bf);

  // out = y @ out_w^T + out_b  (fp32 out)
  gemm_bf16<false><<<dim3(DMODEL/128, T_TOK/128), 256, 0, stream>>>(
      y_bf, outw_bf, out_b, out, T_TOK, DMODEL, DMODEL);
}

// Round 3
// 556.168 us; speedup vs baseline: 3.1010x; 1.0777x over previous
//
#include <hip/hip_runtime.h>
#include <hip/hip_bf16.h>
#include <cmath>

#define T_TOK 8192
#define DMODEL 1024
#define NHEAD 8
#define DH 128
#define NEXP 8
#define NNE 64      // NHEAD*NEXP
#define DHID 512

typedef __bf16 bf16x8 __attribute__((ext_vector_type(8)));
typedef float f32x4 __attribute__((ext_vector_type(4)));
typedef unsigned short u16x8 __attribute__((ext_vector_type(8)));

#define GLDS16(g, l) __builtin_amdgcn_global_load_lds( \
    (const __attribute__((address_space(1))) unsigned int*)(g), \
    (__attribute__((address_space(3))) unsigned int*)(l), 16, 0, 0)

static __device__ inline unsigned short f2bf(float f) {
  return __builtin_bit_cast(unsigned short, __float2bfloat16(f));
}
static __device__ inline float bf2f(unsigned short u) {
  unsigned int v = ((unsigned int)u) << 16;
  return __builtin_bit_cast(float, v);
}

// ---------------- fp32 -> bf16 bulk convert ----------------
__global__ __launch_bounds__(256) void cvt_bf16_kernel(
    const float* __restrict__ src, unsigned short* __restrict__ dst, int n8)
{
  int i = blockIdx.x*256 + threadIdx.x;
  const int stride = gridDim.x*256;
  for (; i < n8; i += stride) {
    const float4 a = *((const float4*)src + (size_t)i*2);
    const float4 b = *((const float4*)src + (size_t)i*2 + 1);
    u16x8 v;
    v[0]=f2bf(a.x); v[1]=f2bf(a.y); v[2]=f2bf(a.z); v[3]=f2bf(a.w);
    v[4]=f2bf(b.x); v[5]=f2bf(b.y); v[6]=f2bf(b.z); v[7]=f2bf(b.w);
    *((u16x8*)dst + i) = v;
  }
}

// ---------------- w_out [ne][f][d] fp32 -> w_outT [ne][d][f] bf16 ----------------
__global__ __launch_bounds__(256) void wout_transpose_kernel(
    const float* __restrict__ w_out, unsigned short* __restrict__ woutT)
{
  const int ne = blockIdx.x;
  const float* src = w_out + (size_t)ne*DHID*DH;
  unsigned short* dst = woutT + (size_t)ne*DH*DHID;
  __shared__ float ws[32][DH+4];
  for (int fc = 0; fc < DHID; fc += 32) {
    __syncthreads();
    for (int i = threadIdx.x; i < 32*DH; i += 256) {
      const int f = i >> 7, d = i & 127;
      ws[f][d] = src[(size_t)(fc+f)*DH + d];
    }
    __syncthreads();
    for (int i = threadIdx.x; i < 32*DH; i += 256) {
      const int d = i >> 5, f = i & 31;
      dst[(size_t)d*DHID + fc + f] = f2bf(ws[f][d]);
    }
  }
}

// ---------------- K0: folded router matrix (fp64) ----------------
__global__ __launch_bounds__(256) void reff_kernel(
    const float* __restrict__ in_w, const float* __restrict__ in_b,
    const float* __restrict__ router_w, double* __restrict__ Rt, double* __restrict__ lb)
{
  const int ne = blockIdx.x;
  const int n  = ne >> 3;
  __shared__ double rw[DH];
  for (int d = threadIdx.x; d < DH; d += 256) rw[d] = (double)router_w[ne*DH + d];
  __syncthreads();
  for (int j = threadIdx.x; j < DMODEL; j += 256) {
    double acc = 0.0;
    #pragma unroll 4
    for (int d = 0; d < DH; ++d)
      acc += (double)in_w[(size_t)(n*DH + d)*DMODEL + j] * rw[d];
    Rt[(size_t)j*NNE + ne] = acc;
  }
  if (threadIdx.x == 0) {
    double acc = 0.0;
    for (int d = 0; d < DH; ++d) acc += (double)in_b[n*DH + d] * rw[d];
    lb[ne] = acc;
  }
}

// ---------------- K1: fp64 logits + top-2, tiled GEMM structure ----------------
// 256 blocks x 512 threads. Block = 32 tokens x 64 ne. thread = (ne = lane, wave = k-slice).
// Per 128-k chunk: stage x as fp64 in LDS; wave w covers kk in [w*16, w*16+16).
// 32 independent fp64 accumulator chains per thread -> latency fully hidden by ILP.
__global__ __launch_bounds__(512) void router_kernel(
    const float* __restrict__ x, const double* __restrict__ Rt, const double* __restrict__ lb,
    int* __restrict__ counts, int* __restrict__ lists, float* __restrict__ wbuf)
{
  const int t0 = blockIdx.x << 5;             // 32 tokens per block
  __shared__ double xd[32][132];              // 33 KB (pad 4: staging writes ~2-way)
  __shared__ double red[32][64];              // 16 KB partial/logit buffer
  const int tid = threadIdx.x;
  const int ne = tid & 63;                    // lane = ne (coalesced Rt reads)
  const int w  = tid >> 6;                    // wave 0..7 = k-slice

  double acc[32];
  #pragma unroll
  for (int i = 0; i < 32; ++i) acc[i] = 0.0;

  const int stok = tid >> 4;                  // staging: token 0..31
  const int skb  = (tid & 15) << 3;           // staging: k offset 0..120

  for (int c = 0; c < DMODEL; c += 128) {
    __syncthreads();                          // previous chunk's reads complete
    {
      const float* gx = x + (size_t)(t0 + stok)*DMODEL + c + skb;
      const float4 v0 = *(const float4*)gx;
      const float4 v1 = *(const float4*)(gx + 4);
      xd[stok][skb+0] = (double)v0.x; xd[stok][skb+1] = (double)v0.y;
      xd[stok][skb+2] = (double)v0.z; xd[stok][skb+3] = (double)v0.w;
      xd[stok][skb+4] = (double)v1.x; xd[stok][skb+5] = (double)v1.y;
      xd[stok][skb+6] = (double)v1.z; xd[stok][skb+7] = (double)v1.w;
    }
    __syncthreads();
    const int kbase = c + (w << 4);
    #pragma unroll
    for (int kk = 0; kk < 16; kk += 2) {
      const double rt0 = Rt[(size_t)(kbase + kk    )*NNE + ne];
      const double rt1 = Rt[(size_t)(kbase + kk + 1)*NNE + ne];
      const int kl = (w << 4) + kk;
      #pragma unroll
      for (int tok = 0; tok < 32; ++tok) {
        const double2 xv = *(const double2*)&xd[tok][kl];   // uniform -> broadcast
        acc[tok] += xv.x * rt0;
        acc[tok] += xv.y * rt1;
      }
    }
  }

  // deterministic cross-wave reduction (ascending wave order, one writer/elem/pass)
  __syncthreads();
  if (w == 0) {
    #pragma unroll
    for (int tok = 0; tok < 32; ++tok) red[tok][ne] = acc[tok];
  }
  __syncthreads();
  for (int s = 1; s < 8; ++s) {
    if (w == s) {
      #pragma unroll
      for (int tok = 0; tok < 32; ++tok) red[tok][ne] += acc[tok];
    }
    __syncthreads();
  }

  // top-2 + softmax weights + bucket scatter (256 threads: tok x head)
  if (tid < 256) {
    const int tok = tid >> 3;
    const int n   = tid & 7;
    double l[NEXP];
    #pragma unroll
    for (int e = 0; e < NEXP; ++e) l[e] = red[tok][n*NEXP + e] + lb[n*NEXP + e];
    int e1 = 0; double v1 = l[0];
    #pragma unroll
    for (int e = 1; e < NEXP; ++e) if (l[e] > v1) { v1 = l[e]; e1 = e; }
    int e2 = -1; double v2 = -1.0e300;
    #pragma unroll
    for (int e = 0; e < NEXP; ++e) if (e != e1 && l[e] > v2) { v2 = l[e]; e2 = e; }
    const double ed = exp(v2 - v1);
    const float w1 = (float)(1.0 / (1.0 + ed));
    const float w2 = (float)(ed / (1.0 + ed));
    const int gtok = t0 + tok;
    const int b1 = n*NEXP + e1, b2 = n*NEXP + e2;
    const int p1 = atomicAdd(&counts[b1], 1);
    lists[(size_t)b1*T_TOK + p1] = gtok*2;        // slot 0
    const int p2 = atomicAdd(&counts[b2], 1);
    lists[(size_t)b2*T_TOK + p2] = gtok*2 + 1;    // slot 1
    wbuf[(size_t)(gtok*NHEAD + n)*2 + 0] = w1;
    wbuf[(size_t)(gtok*NHEAD + n)*2 + 1] = w2;
  }
}

// ---------------- dense GEMM: C[M][N] = A[M][K] * B[N][K]^T + bias, bf16 MFMA ----------------
template<bool BF16OUT>
__global__ __launch_bounds__(256) void gemm_bf16(
    const unsigned short* __restrict__ A, const unsigned short* __restrict__ B,
    const float* __restrict__ bias, void* __restrict__ Cv,
    const int M, const int N, const int K)
{
  __shared__ __align__(16) unsigned short As[128*32];
  __shared__ __align__(16) unsigned short Bs[128*32];
  const int t = threadIdx.x;
  const int lane = t & 63, w = t >> 6;
  const int bm = blockIdx.y << 7, bn = blockIdx.x << 7;
  const int wm = (w & 1) << 6, wn = (w >> 1) << 6;
  f32x4 acc[4][4];
  #pragma unroll
  for (int i = 0; i < 4; ++i)
    #pragma unroll
    for (int j = 0; j < 4; ++j)
      acc[i][j] = (f32x4){0.f, 0.f, 0.f, 0.f};

  const int srow = t >> 2;
  const int skb = (t & 3) << 3;
  const unsigned short* gA = A + (size_t)(bm + srow)*K + skb;
  const unsigned short* gB = B + (size_t)(bn + srow)*K + skb;
  const size_t rowK64 = (size_t)64*K;
  char* lA = (char*)As + t*16;
  char* lB = (char*)Bs + t*16;
  const int rlo = lane & 15;
  const int khi = (lane >> 4) << 4;

  for (int k0 = 0; k0 < K; k0 += 32) {
    GLDS16(gA + k0,          lA);
    GLDS16(gA + rowK64 + k0, lA + 4096);
    GLDS16(gB + k0,          lB);
    GLDS16(gB + rowK64 + k0, lB + 4096);
    __syncthreads();
    bf16x8 av[4], bv[4];
    #pragma unroll
    for (int i = 0; i < 4; ++i) {
      av[i] = *(const bf16x8*)((const char*)As + (wm + i*16 + rlo)*64 + khi);
      bv[i] = *(const bf16x8*)((const char*)Bs + (wn + i*16 + rlo)*64 + khi);
    }
    #pragma unroll
    for (int i = 0; i < 4; ++i)
      #pragma unroll
      for (int j = 0; j < 4; ++j)
        acc[i][j] = __builtin_amdgcn_mfma_f32_16x16x32_bf16(av[i], bv[j], acc[i][j], 0, 0, 0);
    __syncthreads();
  }
  const int rq = (lane >> 4) << 2;
  #pragma unroll
  for (int j = 0; j < 4; ++j) {
    const int col = bn + wn + j*16 + rlo;
    const float bb = bias[col];
    #pragma unroll
    for (int i = 0; i < 4; ++i) {
      const int row0 = bm + wm + i*16 + rq;
      #pragma unroll
      for (int r = 0; r < 4; ++r) {
        const float v = acc[i][j][r] + bb;
        if (BF16OUT) ((unsigned short*)Cv)[(size_t)(row0 + r)*N + col] = f2bf(v);
        else         ((float*)Cv)[(size_t)(row0 + r)*N + col] = v;
      }
    }
  }
}

// ---------------- K3: fused expert FFN, bf16 MFMA, bucketed tokens ----------------
__global__ __launch_bounds__(256) void ffn_mfma_kernel(
    const unsigned short* __restrict__ h_bf, const unsigned short* __restrict__ win_bf,
    const unsigned short* __restrict__ woutT_bf, const int* __restrict__ counts,
    const int* __restrict__ lists, unsigned short* __restrict__ ye_buf)
{
  const int ne = blockIdx.x;
  const int n  = ne >> 3;
  const int cnt = counts[ne];
  const int t0 = blockIdx.y << 7;
  if (t0 >= cnt) return;
  const int nt = min(128, cnt - t0);

  __shared__ __align__(16) unsigned short hA[128*128];
  __shared__ __align__(16) unsigned short wInS[64*128];
  __shared__ __align__(16) unsigned short wOutS[128*64];
  __shared__ __align__(16) unsigned short hidS[128*64];

  const int t = threadIdx.x;
  const int lane = t & 63, w = t >> 6;
  const long lbase = (long)ne * T_TOK;

  #pragma unroll
  for (int s = 0; s < 8; ++s) {
    const int o = s*4096 + t*16;
    const int row = o >> 8;
    const int c = (t & 15) ^ (row & 7);
    const int trow = t0 + row;
    const int ts = lists[lbase + (trow < cnt ? trow : t0)];
    const unsigned short* g = h_bf + (size_t)(ts >> 1)*DMODEL + n*DH + c*8;
    GLDS16(g, (char*)hA + o);
  }

  const unsigned short* winB  = win_bf  + (size_t)ne*DHID*DH;
  const unsigned short* woutB = woutT_bf + (size_t)ne*DH*DHID;

  const int wm = (w & 1) << 6;
  const int wf = (w >> 1) << 5;
  const int wd = (w >> 1) << 6;
  const int rlo = lane & 15;
  const int kq  = lane >> 4;

  f32x4 acc2[4][4];
  #pragma unroll
  for (int i = 0; i < 4; ++i)
    #pragma unroll
    for (int j = 0; j < 4; ++j)
      acc2[i][j] = (f32x4){0.f, 0.f, 0.f, 0.f};

  for (int fc = 0; fc < DHID; fc += 64) {
    #pragma unroll
    for (int s = 0; s < 4; ++s) {
      const int o = s*4096 + t*16;
      const int row = o >> 8;
      const int c = (t & 15) ^ (row & 7);
      GLDS16(winB + (size_t)(fc + row)*DH + c*8, (char*)wInS + o);
    }
    #pragma unroll
    for (int s = 0; s < 4; ++s) {
      const int o = s*4096 + t*16;
      const int row = o >> 7;
      const int c = (t & 7) ^ (row & 7);
      GLDS16(woutB + (size_t)row*DHID + fc + c*8, (char*)wOutS + o);
    }
    __syncthreads();

    f32x4 acc1[4][2];
    #pragma unroll
    for (int i = 0; i < 4; ++i) {
      acc1[i][0] = (f32x4){0.f,0.f,0.f,0.f};
      acc1[i][1] = (f32x4){0.f,0.f,0.f,0.f};
    }
    #pragma unroll
    for (int ks = 0; ks < 4; ++ks) {
      const int kb = ks*64 + kq*16;
      bf16x8 a[4], b[2];
      #pragma unroll
      for (int i = 0; i < 4; ++i) {
        const int tr = wm + i*16 + rlo;
        a[i] = *(const bf16x8*)((const char*)hA + tr*256 + (kb ^ ((tr & 7) << 4)));
      }
      #pragma unroll
      for (int j = 0; j < 2; ++j) {
        const int fr = wf + j*16 + rlo;
        b[j] = *(const bf16x8*)((const char*)wInS + fr*256 + (kb ^ ((fr & 7) << 4)));
      }
      #pragma unroll
      for (int i = 0; i < 4; ++i)
        #pragma unroll
        for (int j = 0; j < 2; ++j)
          acc1[i][j] = __builtin_amdgcn_mfma_f32_16x16x32_bf16(a[i], b[j], acc1[i][j], 0, 0, 0);
    }
    #pragma unroll
    for (int i = 0; i < 4; ++i)
      #pragma unroll
      for (int j = 0; j < 2; ++j)
        #pragma unroll
        for (int r = 0; r < 4; ++r) {
          const float v = acc1[i][j][r];
          const float g = 0.5f * v * (1.0f + erff(v * 0.70710678118654752f));
          const int tr = wm + i*16 + kq*4 + r;
          const int f  = wf + j*16 + rlo;
          const int byte = tr*128 + (((f >> 3) ^ (tr & 7)) << 4) + ((f & 7) << 1);
          *(unsigned short*)((char*)hidS + byte) = f2bf(g);
        }
    __syncthreads();

    #pragma unroll
    for (int ks = 0; ks < 2; ++ks) {
      const int kb = ks*64 + kq*16;
      bf16x8 a[4], b[4];
      #pragma unroll
      for (int i = 0; i < 4; ++i) {
        const int tr = wm + i*16 + rlo;
        a[i] = *(const bf16x8*)((const char*)hidS + tr*128 + (kb ^ ((tr & 7) << 4)));
      }
      #pragma unroll
      for (int j = 0; j < 4; ++j) {
        const int dr = wd + j*16 + rlo;
        b[j] = *(const bf16x8*)((const char*)wOutS + dr*128 + (kb ^ ((dr & 7) << 4)));
      }
      #pragma unroll
      for (int i = 0; i < 4; ++i)
        #pragma unroll
        for (int j = 0; j < 4; ++j)
          acc2[i][j] = __builtin_amdgcn_mfma_f32_16x16x32_bf16(a[i], b[j], acc2[i][j], 0, 0, 0);
    }
    __syncthreads();
  }

  #pragma unroll
  for (int i = 0; i < 4; ++i) {
    #pragma unroll
    for (int r = 0; r < 4; ++r) {
      const int tr = wm + i*16 + kq*4 + r;
      if (tr < nt) {
        const int ts = lists[lbase + t0 + tr];
        unsigned short* dst = ye_buf +
            ((((size_t)(ts >> 1))*NHEAD + n)*2 + (ts & 1))*DH + wd;
        #pragma unroll
        for (int j = 0; j < 4; ++j)
          dst[j*16 + rlo] = f2bf(acc2[i][j][r]);
      }
    }
  }
}

// ---------------- K4: gate-weighted combine of the two slots -> y (bf16) ----------------
__global__ __launch_bounds__(256) void combine_kernel(
    const unsigned short* __restrict__ ye_buf, const float* __restrict__ wbuf,
    unsigned short* __restrict__ y_bf)
{
  const int u = blockIdx.x*256 + threadIdx.x;
  const int tn = u >> 4;
  const int ch = u & 15;
  const float w0 = wbuf[(size_t)tn*2 + 0];
  const float w1 = wbuf[(size_t)tn*2 + 1];
  const u16x8 a = *((const u16x8*)ye_buf + (size_t)tn*32 + ch);
  const u16x8 b = *((const u16x8*)ye_buf + (size_t)tn*32 + 16 + ch);
  u16x8 v;
  #pragma unroll
  for (int j = 0; j < 8; ++j)
    v[j] = f2bf(w0*bf2f(a[j]) + w1*bf2f(b[j]));
  *((u16x8*)y_bf + u) = v;
}

// ---------------- launch ----------------
extern "C" void kernel_launch(void* const* d_in, const int* in_sizes, int n_in,
                              void* d_out, int out_size, void* d_ws, size_t ws_size,
                              hipStream_t stream) {
  const float* x        = (const float*)d_in[0];
  const float* in_w     = (const float*)d_in[1];
  const float* in_b     = (const float*)d_in[2];
  const float* router_w = (const float*)d_in[3];
  const float* w_in     = (const float*)d_in[4];
  const float* w_out    = (const float*)d_in[5];
  const float* out_w    = (const float*)d_in[6];
  const float* out_b    = (const float*)d_in[7];
  float* out = (float*)d_out;

  size_t off = 0;
  char* base = (char*)d_ws;
  auto alloc = [&](size_t bytes) -> void* {
    void* p = base + off;
    off += (bytes + 255) & ~(size_t)255;
    return p;
  };
  unsigned short* h_bf    = (unsigned short*)alloc((size_t)T_TOK*DMODEL*2);
  unsigned short* x_bf    = (unsigned short*)alloc((size_t)T_TOK*DMODEL*2);
  unsigned short* inw_bf  = (unsigned short*)alloc((size_t)DMODEL*DMODEL*2);
  unsigned short* outw_bf = (unsigned short*)alloc((size_t)DMODEL*DMODEL*2);
  unsigned short* win_bf  = (unsigned short*)alloc((size_t)NNE*DHID*DH*2);
  unsigned short* woutT_bf= (unsigned short*)alloc((size_t)NNE*DH*DHID*2);
  unsigned short* ye_buf  = (unsigned short*)alloc((size_t)T_TOK*NHEAD*2*DH*2);
  float*  wbuf   = (float*) alloc((size_t)T_TOK*NHEAD*2*4);
  double* Rt     = (double*)alloc((size_t)DMODEL*NNE*8);
  double* lb     = (double*)alloc(NNE*8);
  int*    counts = (int*)   alloc(NNE*4);
  int*    lists  = (int*)   alloc((size_t)NNE*T_TOK*4);
  unsigned short* y_bf = x_bf;

  hipMemsetAsync(counts, 0, NNE*4, stream);

  cvt_bf16_kernel<<<2048, 256, 0, stream>>>(x,     x_bf,    T_TOK*DMODEL/8);
  cvt_bf16_kernel<<<512,  256, 0, stream>>>(in_w,  inw_bf,  DMODEL*DMODEL/8);
  cvt_bf16_kernel<<<512,  256, 0, stream>>>(out_w, outw_bf, DMODEL*DMODEL/8);
  cvt_bf16_kernel<<<2048, 256, 0, stream>>>(w_in,  win_bf,  NNE*DHID*DH/8);
  wout_transpose_kernel<<<NNE, 256, 0, stream>>>(w_out, woutT_bf);

  reff_kernel  <<<NNE, 256, 0, stream>>>(in_w, in_b, router_w, Rt, lb);
  router_kernel<<<T_TOK/32, 512, 0, stream>>>(x, Rt, lb, counts, lists, wbuf);

  gemm_bf16<true><<<dim3(DMODEL/128, T_TOK/128), 256, 0, stream>>>(
      x_bf, inw_bf, in_b, h_bf, T_TOK, DMODEL, DMODEL);

  ffn_mfma_kernel<<<dim3(NNE, T_TOK/128), 256, 0, stream>>>(
      h_bf, win_bf, woutT_bf, counts, lists, ye_buf);

  combine_kernel<<<T_TOK*NHEAD*16/256, 256, 0, stream>>>(ye_buf, wbuf, y_bf);

  gemm_bf16<false><<<dim3(DMODEL/128, T_TOK/128), 256, 0, stream>>>(
      y_bf, outw_bf, out_b, out, T_TOK, DMODEL, DMODEL);
}